// Round 1
// baseline (4601.700 us; speedup 1.0000x reference)
//
#include <hip/hip_runtime.h>
#include <math.h>

#define BB 8
#define CC 512

// ---------------------------------------------------------------------------
// Fused activation1d: polyphase 2x upsample (k=6, pad 2/3, crop 2/2)
//   -> SnakeBeta -> stride-2 lowpass (k=12, pad 5).  Depthwise, memory-bound.
// One block per (b,c) row; tiles of ACT_TT outputs.
// ---------------------------------------------------------------------------
#define ACT_TT 256

__global__ __launch_bounds__(256) void act_kernel(
    const float* __restrict__ xin, float* __restrict__ yout,
    const float* __restrict__ up_w,    // [2C][6]
    const float* __restrict__ down_w,  // [C][12]
    const float* __restrict__ alpha,   // [C]
    const float* __restrict__ beta,    // [C]
    int Lin)
{
    const int Lout = Lin - 2;
    const int row  = blockIdx.x;          // b*C + c
    const int c    = row & (CC - 1);
    const int tid  = threadIdx.x;

    __shared__ float xs[ACT_TT + 12];         // x window (with halo)
    __shared__ float sbuf[2 * ACT_TT + 12];   // snake(upsampled) tile

    // per-channel params (block-uniform)
    const float a     = expf(alpha[c]);
    const float inv2b = 1.0f / (2.0f * expf(beta[c]) + 1e-9f);

    float uw0[6], uw1[6], dw[12];
#pragma unroll
    for (int k = 0; k < 6; ++k) {
        uw0[k] = up_w[(2 * c    ) * 6 + k];
        uw1[k] = up_w[(2 * c + 1) * 6 + k];
    }
#pragma unroll
    for (int j = 0; j < 12; ++j) dw[j] = down_w[c * 12 + j];

    const float* xr = xin  + (size_t)row * Lin;
    float*       yr = yout + (size_t)row * Lout;

    const int smax = 2 * Lin - 4;   // length of cropped upsampled signal

    for (int t0 = 0; t0 < Lout; t0 += ACT_TT) {
        // ---- stage x window: xin[t0-4 .. t0+TT+6] ----
        for (int i = tid; i < ACT_TT + 11; i += 256) {
            int g = t0 - 4 + i;
            xs[i] = (g >= 0 && g < Lin) ? xr[g] : 0.0f;
        }
        __syncthreads();

        // ---- snake(upsample) for s in [2*t0-5, 2*t0+2*TT+4] ----
        const int s0 = 2 * t0 - 5;
        for (int i = tid; i < 2 * ACT_TT + 10; i += 256) {
            int s = s0 + i;
            float val = 0.0f;
            if (s >= 0 && s < smax) {
                int sp = s + 2;            // pre-crop index
                int r  = sp & 1;           // phase
                int tt = sp >> 1;          // upsample conv position
                int xi = tt - t0 + 2;      // xs index for k=0 (== tt-2 - (t0-4))
                float u = 0.0f;
#pragma unroll
                for (int k = 0; k < 6; ++k) {
                    float w = r ? uw1[k] : uw0[k];
                    u = fmaf(xs[xi + k], w, u);
                }
                // SnakeBeta: u + (1 - cos(2*a*u)) * inv2b   (snake(0)=0)
                val = fmaf(1.0f - cosf(2.0f * a * u), inv2b, u);
            }
            sbuf[i] = val;
        }
        __syncthreads();

        // ---- stride-2 k=12 lowpass: y[t] = sum_j sb[2t+j-5]*dw[j] ----
        int t = t0 + tid;
        if (t < Lout) {
            float y = 0.0f;
#pragma unroll
            for (int j = 0; j < 12; ++j)
                y = fmaf(sbuf[2 * tid + j], dw[j], y);
            yr[t] = y;
        }
        __syncthreads();   // protect sbuf/xs before next tile
    }
}

// ---------------------------------------------------------------------------
// C->C conv1d, k=3, pad=1 (+bias, optional residual add).
// Block: 256 thr = 16 tx (t) x 16 ty (co). Tile: 64 t x 64 co, 4x4 per thread.
// Loop ci in chunks of 16; x window + transposed weights staged in LDS.
// ---------------------------------------------------------------------------
#define CI_TILE 16

__global__ __launch_bounds__(256) void conv3_kernel(
    const float* __restrict__ xin, float* __restrict__ yout,
    const float* __restrict__ w,      // [C][C][3]
    const float* __restrict__ bias,   // [C]
    const float* __restrict__ resid,  // nullable
    int L, int res_stride)
{
    const int tid = threadIdx.x;
    const int tx  = tid & 15;
    const int ty  = tid >> 4;
    const int t0  = blockIdx.x * 64;
    const int co0 = blockIdx.y * 64;
    const int b   = blockIdx.z;

    __shared__ float xs[CI_TILE * 68];            // [ci][68] (66 used, 16B-aligned rows)
    __shared__ float wl[CI_TILE * 64 * 3];        // [ci][co][k]

    float acc[4][4];
#pragma unroll
    for (int j = 0; j < 4; ++j)
#pragma unroll
        for (int d = 0; d < 4; ++d) acc[j][d] = 0.0f;

    const size_t in_base = (size_t)b * CC * L;

    for (int ci0 = 0; ci0 < CC; ci0 += CI_TILE) {
        // stage x: row ty handles channel ci0+ty
        {
            const float* xrow = xin + in_base + (size_t)(ci0 + ty) * L;
#pragma unroll
            for (int idx = tx; idx < 66; idx += 16) {
                int g = t0 - 1 + idx;
                xs[ty * 68 + idx] = (g >= 0 && g < L) ? xrow[g] : 0.0f;
            }
        }
        // stage w transposed: wl[ci][co][k] = w[co0+co][ci0+ci][k]
        for (int i = tid; i < CI_TILE * 64 * 3; i += 256) {
            int co = i / 48;
            int rm = i - co * 48;
            int ci = rm / 3;
            int k  = rm - ci * 3;
            wl[ci * 192 + co * 3 + k] =
                w[(size_t)(co0 + co) * (CC * 3) + (ci0 + ci) * 3 + k];
        }
        __syncthreads();

#pragma unroll
        for (int ci = 0; ci < CI_TILE; ++ci) {
            const float4 xa = *reinterpret_cast<const float4*>(&xs[ci * 68 + tx * 4]);
            const float2 xb = *reinterpret_cast<const float2*>(&xs[ci * 68 + tx * 4 + 4]);
            const float xv[6] = {xa.x, xa.y, xa.z, xa.w, xb.x, xb.y};
            const float4 wa = *reinterpret_cast<const float4*>(&wl[ci * 192 + ty * 12]);
            const float4 wb = *reinterpret_cast<const float4*>(&wl[ci * 192 + ty * 12 + 4]);
            const float4 wc = *reinterpret_cast<const float4*>(&wl[ci * 192 + ty * 12 + 8]);
            const float wv[12] = {wa.x, wa.y, wa.z, wa.w, wb.x, wb.y,
                                  wb.z, wb.w, wc.x, wc.y, wc.z, wc.w};
#pragma unroll
            for (int j = 0; j < 4; ++j) {
                float w0 = wv[j * 3], w1 = wv[j * 3 + 1], w2 = wv[j * 3 + 2];
#pragma unroll
                for (int d = 0; d < 4; ++d)
                    acc[j][d] = fmaf(w0, xv[d],
                                fmaf(w1, xv[d + 1],
                                fmaf(w2, xv[d + 2], acc[j][d])));
            }
        }
        __syncthreads();
    }

    // epilogue
    const size_t out_base = (size_t)b * CC * L;
    const int t = t0 + tx * 4;
#pragma unroll
    for (int j = 0; j < 4; ++j) {
        const int co = co0 + ty * 4 + j;
        const float bv = bias[co];
        float v[4];
#pragma unroll
        for (int d = 0; d < 4; ++d) v[d] = acc[j][d] + bv;
        if (resid) {
            const float* rrow = resid + ((size_t)b * CC + co) * res_stride + t;
            if (t + 3 < L) {
                const float4 rv = *reinterpret_cast<const float4*>(rrow);
                v[0] += rv.x; v[1] += rv.y; v[2] += rv.z; v[3] += rv.w;
            } else {
#pragma unroll
                for (int d = 0; d < 4; ++d)
                    if (t + d < L) v[d] += rrow[d];
            }
        }
        float* orow = yout + out_base + (size_t)co * L + t;
        if (t + 3 < L) {
            *reinterpret_cast<float4*>(orow) = make_float4(v[0], v[1], v[2], v[3]);
        } else {
#pragma unroll
            for (int d = 0; d < 4; ++d)
                if (t + d < L) orow[d] = v[d];
        }
    }
}

// ---------------------------------------------------------------------------
extern "C" void kernel_launch(void* const* d_in, const int* in_sizes, int n_in,
                              void* d_out, int out_size, void* d_ws, size_t ws_size,
                              hipStream_t stream)
{
    const float* x       = (const float*)d_in[0];
    const float* up_w1   = (const float*)d_in[1];
    const float* down_w1 = (const float*)d_in[2];
    const float* alpha1  = (const float*)d_in[3];
    const float* beta1   = (const float*)d_in[4];
    const float* up_w2   = (const float*)d_in[5];
    const float* down_w2 = (const float*)d_in[6];
    const float* alpha2  = (const float*)d_in[7];
    const float* beta2   = (const float*)d_in[8];
    const float* c1_w    = (const float*)d_in[9];
    const float* c1_b    = (const float*)d_in[10];
    const float* c2_w    = (const float*)d_in[11];
    const float* c2_b    = (const float*)d_in[12];
    float* out = (float*)d_out;

    const int T  = 8192;
    const int L1 = T - 2;   // 8190: act1 out / conv1 in-out / act2 in
    const int L2 = T - 4;   // 8188: act2 out / conv2 in-out

    float* bufA = (float*)d_ws;                        // act1 out (B,C,L1); later act2 out (B,C,L2)
    float* bufB = bufA + (size_t)BB * CC * L1;         // conv1 out (B,C,L1)

    // act1: x (B,C,T) -> bufA (B,C,L1)
    act_kernel<<<dim3(BB * CC), 256, 0, stream>>>(x, bufA, up_w1, down_w1, alpha1, beta1, T);
    // conv1: bufA -> bufB
    conv3_kernel<<<dim3((L1 + 63) / 64, CC / 64, BB), 256, 0, stream>>>(
        bufA, bufB, c1_w, c1_b, nullptr, L1, 0);
    // act2: bufB (L1) -> bufA (L2)
    act_kernel<<<dim3(BB * CC), 256, 0, stream>>>(bufB, bufA, up_w2, down_w2, alpha2, beta2, L1);
    // conv2 + residual: bufA (L2) + x[:, :, :L2] -> out
    conv3_kernel<<<dim3((L2 + 63) / 64, CC / 64, BB), 256, 0, stream>>>(
        bufA, out, c2_w, c2_b, x, L2, T);
}

// Round 2
// 885.815 us; speedup vs baseline: 5.1949x; 5.1949x over previous
//
#include <hip/hip_runtime.h>
#include <math.h>

#define CC 512
#define BB 8
#define TTOT 8192
#define LEN1 (TTOT - 2)   // 8190
#define LEN2 (TTOT - 4)   // 8188
#define GPRE 8
#define GPOST 24
#define PITCH (GPRE + TTOT + GPOST)   // 8224 rows per batch (t-major buffers)

typedef unsigned short u16;
typedef __bf16 v8bf __attribute__((ext_vector_type(8)));
typedef float v4f __attribute__((ext_vector_type(4)));

__device__ __forceinline__ u16 f2b(float f) {
    unsigned u = __float_as_uint(f);
    unsigned r = (u + 0x7FFFu + ((u >> 16) & 1u)) >> 16;
    return (u16)r;
}
__device__ __forceinline__ float b2f(u16 h) {
    return __uint_as_float(((unsigned)h) << 16);
}
__device__ __forceinline__ void ldsdma16(const void* g, void* l) {
    __builtin_amdgcn_global_load_lds(
        (const __attribute__((address_space(1))) unsigned int*)g,
        (__attribute__((address_space(3))) unsigned int*)l, 16, 0, 0);
}

// ---------------------------------------------------------------------------
// Weight prep: w[co][ci][3] f32 -> wr[k][co][ci] bf16
// ---------------------------------------------------------------------------
__global__ __launch_bounds__(256) void wprep_kernel(const float* __restrict__ w,
                                                    u16* __restrict__ wr)
{
    int idx = blockIdx.x * 256 + threadIdx.x;     // co*512 + ci
    int co = idx >> 9, ci = idx & 511;
    const float* s = w + (size_t)idx * 3;
#pragma unroll
    for (int k = 0; k < 3; ++k)
        wr[((size_t)k * CC + co) * CC + ci] = f2b(s[k]);
}

// ---------------------------------------------------------------------------
// Zero guard rows of a t-major buffer: rows [-GPRE,0) and [Lstart, Lstart+GPOST)
// xt0 points at row 0 of batch 0.
// ---------------------------------------------------------------------------
__global__ __launch_bounds__(256) void zguard_kernel(u16* xt0, int Lstart)
{
    int r = blockIdx.x;            // 0..31
    int b = blockIdx.y;
    int row = (r < GPRE) ? (r - GPRE) : (Lstart + (r - GPRE));
    u16* p = xt0 + ((size_t)b * PITCH + row) * CC;
    p[threadIdx.x] = 0;
    p[threadIdx.x + 256] = 0;
}

// ---------------------------------------------------------------------------
// Fused activation1d producing t-major bf16 (row0-based, pitch PITCH).
// Tile: 32 channels x 128 t-outputs. TMAJ selects input layout:
//   false: c-major f32 (batch stride CC*Lin), true: t-major bf16 (pitch PITCH).
// ---------------------------------------------------------------------------
template<bool TMAJ>
__global__ __launch_bounds__(256) void actT_kernel(
    const void* __restrict__ xin_v,
    u16* __restrict__ yout,          // row0 of batch0, t-major bf16
    const float* __restrict__ up_w,  // [2C][6]
    const float* __restrict__ down_w,// [C][12]
    const float* __restrict__ alpha,
    const float* __restrict__ beta,
    int Lin)
{
    const int Lout = Lin - 2;
    const int smax = 2 * Lin - 4;
    const int tid = threadIdx.x;
    const int t0 = blockIdx.x * 128;
    const int c0 = blockIdx.y * 32;
    const int b  = blockIdx.z;

    __shared__ float xs[140 * 33];   // [t-window 0..138][c]
    __shared__ float sb[266 * 33];   // [sloc][c]

    // ---- P1: load x window t0-4 .. t0+134 (139 rows) x 32 c ----
    if (!TMAJ) {
        const float* xcb = (const float*)xin_v + ((size_t)b * CC + c0) * Lin;
        int lane = tid & 63, w = tid >> 6;
#pragma unroll
        for (int rr = 0; rr < 8; ++rr) {
            int c = w * 8 + rr;
            const float* xr = xcb + (size_t)c * Lin;
            for (int i = lane; i < 139; i += 64) {
                int g = t0 - 4 + i;
                xs[i * 33 + c] = (g >= 0 && g < Lin) ? xr[g] : 0.0f;
            }
        }
    } else {
        const u16* xb = (const u16*)xin_v + (size_t)b * PITCH * CC + c0;
        int pr = tid & 15, rq = tid >> 4;
        for (int r0 = 0; r0 < 139; r0 += 16) {
            int row = r0 + rq;
            if (row < 139) {
                int t = t0 - 4 + row;   // within [-8, Lin+GPOST) guards
                const u16* gp = xb + (ptrdiff_t)t * CC + pr * 2;
                ushort2 u = *(const ushort2*)gp;
                xs[row * 33 + pr * 2]     = b2f(u.x);
                xs[row * 33 + pr * 2 + 1] = b2f(u.y);
            }
        }
    }
    __syncthreads();

    // ---- P2: snake(upsample) -> sb ----
    {
        int c = tid & 31, sg = tid >> 5;
        int cg = c0 + c;
        float a     = expf(alpha[cg]);
        float inv2b = 1.0f / (2.0f * expf(beta[cg]) + 1e-9f);
        float uwa[6], uwb[6];
#pragma unroll
        for (int k = 0; k < 6; ++k) {
            uwa[k] = up_w[(2 * cg) * 6 + k];
            uwb[k] = up_w[(2 * cg + 1) * 6 + k];
        }
        const int s_lo = 2 * t0 - 5;
        for (int sl = sg; sl < 266; sl += 8) {
            int s = s_lo + sl;
            float v = 0.0f;
            if (s >= 0 && s < smax) {
                int sp = s + 2;
                int r  = sp & 1;
                int tt = sp >> 1;
                int xi = tt - t0 + 2;    // 0..133
                float u = 0.0f;
#pragma unroll
                for (int k = 0; k < 6; ++k) {
                    float wk = r ? uwb[k] : uwa[k];
                    u = fmaf(xs[(xi + k) * 33 + c], wk, u);
                }
                v = fmaf(1.0f - __cosf(2.0f * a * u), inv2b, u);
            }
            sb[sl * 33 + c] = v;
        }
    }
    __syncthreads();

    // ---- P3: stride-2 k=12 lowpass, write t-major bf16 ----
    {
        int c = tid & 31, tg = tid >> 5;
        int cg = c0 + c;
        float dw[12];
#pragma unroll
        for (int j = 0; j < 12; ++j) dw[j] = down_w[cg * 12 + j];
        u16* yb = yout + (size_t)b * PITCH * CC;
        for (int tl = tg; tl < 128; tl += 8) {
            float y = 0.0f;
#pragma unroll
            for (int j = 0; j < 12; ++j)
                y = fmaf(sb[(2 * tl + j) * 33 + c], dw[j], y);
            int t = t0 + tl;
            if (t < Lout) yb[(size_t)t * CC + cg] = f2b(y);
        }
    }
}

// ---------------------------------------------------------------------------
// k=3 pad=1 conv as bf16 MFMA GEMM over t-major input.
// Tile 256 t x 128 co, K = 3 x 512 ci. 4 waves, each 128t x 64co (8x4 MFMA tiles).
// ORIENT 0: D[m=t][n=co], writes t-major bf16 (+bias).
// ORIENT 1: D[m=co][n=t], writes c-major f32 (+bias+residual).
// ---------------------------------------------------------------------------
template<int ORIENT>
__global__ __launch_bounds__(256, 2) void convg_kernel(
    const u16* __restrict__ xt,     // row0 of batch0, t-major bf16, pitch PITCH
    const u16* __restrict__ wr,     // [3][512][512] bf16
    const float* __restrict__ bias, // [512]
    u16* __restrict__ yt,           // ORIENT 0 output (row0 base)
    float* __restrict__ out,        // ORIENT 1 output (B,C,Lout)
    const float* __restrict__ resid,// ORIENT 1 residual (B,C,TTOT)
    int Lout)
{
    const int tid  = threadIdx.x;
    const int lane = tid & 63, wid = tid >> 6;
    const int wt = wid & 1, wc = wid >> 1;
    const int l15 = lane & 15, q = lane >> 4;
    const int t0  = blockIdx.x * 256;
    const int co0 = blockIdx.y * 128;
    const int b   = blockIdx.z;

    __shared__ __align__(16) u16 xsm[4 * 264 * 8];    // (g*264+row)*8
    __shared__ __align__(16) u16 wsm[3 * 4 * 128 * 8];// ((k*4+g)*128+co)*8

    const u16* xb = xt + (size_t)b * PITCH * CC;      // row 0 of batch b

    v4f acc[8][4];
#pragma unroll
    for (int m = 0; m < 8; ++m)
#pragma unroll
        for (int n = 0; n < 4; ++n)
#pragma unroll
            for (int r = 0; r < 4; ++r) acc[m][n][r] = 0.0f;

    for (int ci0 = 0; ci0 < CC; ci0 += 32) {
        // ---- stage X: rows t0-1 .. t0+262 (264), granule-major; 1056 tasks ----
        for (int ii = wid; ii < 17; ii += 4) {
            int task = ii * 64 + lane;
            if (task < 1056) {
                int g   = task / 264;
                int row = task - g * 264;
                int tix = t0 - 1 + row;
                const u16* gp = xb + (ptrdiff_t)tix * CC + ci0 + g * 8;
                ldsdma16(gp, xsm + (size_t)ii * 64 * 8);
            }
        }
        // ---- stage W: 1536 tasks = k*512 + g*128 + co ----
        for (int ii = wid; ii < 24; ii += 4) {
            int task = ii * 64 + lane;
            int k  = task >> 9;
            int gg = (task >> 7) & 3;
            int co = task & 127;
            const u16* gp = wr + ((size_t)(k * CC + co0 + co)) * CC + ci0 + gg * 8;
            ldsdma16(gp, wsm + (size_t)ii * 64 * 8);
        }
        __syncthreads();

#pragma unroll
        for (int k = 0; k < 3; ++k) {
            v8bf wf[4];
#pragma unroll
            for (int n = 0; n < 4; ++n) {
                int co_l = wc * 64 + n * 16 + l15;
                wf[n] = *(const v8bf*)(wsm + (((k * 4 + q) * 128) + co_l) * 8);
            }
#pragma unroll
            for (int m = 0; m < 8; ++m) {
                int r = wt * 128 + m * 16 + l15 + k;   // row -> t = t0 + (...) + k-1
                v8bf xf = *(const v8bf*)(xsm + ((q * 264) + r) * 8);
#pragma unroll
                for (int n = 0; n < 4; ++n) {
                    if (ORIENT == 0)
                        acc[m][n] = __builtin_amdgcn_mfma_f32_16x16x32_bf16(
                            xf, wf[n], acc[m][n], 0, 0, 0);
                    else
                        acc[m][n] = __builtin_amdgcn_mfma_f32_16x16x32_bf16(
                            wf[n], xf, acc[m][n], 0, 0, 0);
                }
            }
        }
        __syncthreads();
    }

    if (ORIENT == 0) {
        // D[m=t][n=co]: col(lane&15)=co, row(q*4+reg)=t-local
        float bv[4];
#pragma unroll
        for (int n = 0; n < 4; ++n) bv[n] = bias[co0 + wc * 64 + n * 16 + l15];
        u16* yb = yt + (size_t)b * PITCH * CC;
#pragma unroll
        for (int m = 0; m < 8; ++m) {
            int tb = t0 + wt * 128 + m * 16;
#pragma unroll
            for (int rg = 0; rg < 4; ++rg) {
                int t = tb + q * 4 + rg;
                if (t < Lout) {
#pragma unroll
                    for (int n = 0; n < 4; ++n) {
                        int co = co0 + wc * 64 + n * 16 + l15;
                        yb[(size_t)t * CC + co] = f2b(acc[m][n][rg] + bv[n]);
                    }
                }
            }
        }
    } else {
        // D[m=co][n=t]: col(lane&15)=t-local, row(q*4+reg)=co-local
        float bv[4][4];
#pragma unroll
        for (int n = 0; n < 4; ++n)
#pragma unroll
            for (int rg = 0; rg < 4; ++rg)
                bv[n][rg] = bias[co0 + wc * 64 + n * 16 + q * 4 + rg];
#pragma unroll
        for (int n = 0; n < 4; ++n) {
#pragma unroll
            for (int rg = 0; rg < 4; ++rg) {
                int co = co0 + wc * 64 + n * 16 + q * 4 + rg;
                float* orow = out + ((size_t)b * CC + co) * Lout;
                const float* rrow = resid + ((size_t)b * CC + co) * TTOT;
#pragma unroll
                for (int m = 0; m < 8; ++m) {
                    int t = t0 + wt * 128 + m * 16 + l15;
                    if (t < Lout)
                        orow[t] = acc[m][n][rg] + bv[n][rg] + rrow[t];
                }
            }
        }
    }
}

// ---------------------------------------------------------------------------
extern "C" void kernel_launch(void* const* d_in, const int* in_sizes, int n_in,
                              void* d_out, int out_size, void* d_ws, size_t ws_size,
                              hipStream_t stream)
{
    const float* x       = (const float*)d_in[0];
    const float* up_w1   = (const float*)d_in[1];
    const float* down_w1 = (const float*)d_in[2];
    const float* alpha1  = (const float*)d_in[3];
    const float* beta1   = (const float*)d_in[4];
    const float* up_w2   = (const float*)d_in[5];
    const float* down_w2 = (const float*)d_in[6];
    const float* alpha2  = (const float*)d_in[7];
    const float* beta2   = (const float*)d_in[8];
    const float* c1_w    = (const float*)d_in[9];
    const float* c1_b    = (const float*)d_in[10];
    const float* c2_w    = (const float*)d_in[11];
    const float* c2_b    = (const float*)d_in[12];
    float* out = (float*)d_out;

    u16* wr1  = (u16*)d_ws;                       // 786432 elems
    u16* wr2  = wr1 + 786432;
    u16* xTa0 = wr2 + 786432;                     // buffer base (with guards)
    u16* xTa  = xTa0 + GPRE * CC;                 // row0 of batch0
    u16* xTb0 = xTa0 + (size_t)BB * PITCH * CC;
    u16* xTb  = xTb0 + GPRE * CC;

    // weight transforms (tiny)
    wprep_kernel<<<1024, 256, 0, stream>>>(c1_w, wr1);
    wprep_kernel<<<1024, 256, 0, stream>>>(c2_w, wr2);
    // guard zeroing
    zguard_kernel<<<dim3(32, 8), 256, 0, stream>>>(xTa, LEN1);
    zguard_kernel<<<dim3(32, 8), 256, 0, stream>>>(xTb, LEN1);

    // act1: x (c-major f32, Lin=8192) -> xTa (t-major bf16, Lout=8190)
    actT_kernel<false><<<dim3(64, 16, 8), 256, 0, stream>>>(
        (const void*)x, xTa, up_w1, down_w1, alpha1, beta1, TTOT);
    // conv1: xTa -> xTb (t-major bf16), Lout=8190
    convg_kernel<0><<<dim3(32, 4, 8), 256, 0, stream>>>(
        xTa, wr1, c1_b, xTb, nullptr, nullptr, LEN1);
    // re-zero xTa guards for length LEN2 (act2 output reuses xTa)
    zguard_kernel<<<dim3(32, 8), 256, 0, stream>>>(xTa, LEN2);
    // act2: xTb (t-major bf16, Lin=8190) -> xTa (t-major bf16, Lout=8188)
    actT_kernel<true><<<dim3(64, 16, 8), 256, 0, stream>>>(
        (const void*)xTb, xTa, up_w2, down_w2, alpha2, beta2, LEN1);
    // conv2 + bias + residual: xTa -> out (c-major f32, Lout=8188)
    convg_kernel<1><<<dim3(32, 4, 8), 256, 0, stream>>>(
        xTa, wr2, c2_b, nullptr, out, x, LEN2);
}